// Round 1
// baseline (492.253 us; speedup 1.0000x reference)
//
#include <hip/hip_runtime.h>
#include <math.h>

#define T_STEPS 32
#define BATCH 64
#define HID 512

// ws layout (floats)
#define WS_WXQ 0        // [8][512]
#define WS_WHQ 4096     // [8][512]
#define WS_BQ  8192     // [8]
#define WS_U   8208     // 128 matrices * 8 floats (U00.x,U00.y,U01.x,U01.y,U10.x,U10.y,U11.x,U11.y)
#define WS_XQ  9232     // [32*64][8]

struct c32 { float x, y; };
__device__ inline c32 cmul(c32 a, c32 b){ return {a.x*b.x - a.y*b.y, a.x*b.y + a.y*b.x}; }
__device__ inline c32 cadd(c32 a, c32 b){ return {a.x+b.x, a.y+b.y}; }

__global__ void precompute_kernel(const float* __restrict__ W_proj,
                                  const float* __restrict__ b_proj,
                                  const float* __restrict__ W_toq,
                                  const float* __restrict__ fP, const float* __restrict__ iP,
                                  const float* __restrict__ gP, const float* __restrict__ oP,
                                  float* __restrict__ ws)
{
    int tid = threadIdx.x; // 256 threads
    // Folded weights Wxq / Whq
    for (int idx = tid; idx < 8 * 1024; idx += 256) {
        int q = idx >> 10, dd = idx & 1023;
        float acc = 0.f;
        for (int p = 0; p < 64; ++p) acc += W_toq[q * 64 + p] * W_proj[p * 1024 + dd];
        if (dd < 512) ws[WS_WXQ + q * 512 + dd] = acc;
        else          ws[WS_WHQ + q * 512 + (dd - 512)] = acc;
    }
    if (tid < 8) {
        float acc = 0.f;
        for (int p = 0; p < 64; ++p) acc += W_toq[tid * 64 + p] * b_proj[p];
        ws[WS_BQ + tid] = acc;
    }
    // Rotation matrices: id = gt*32 + g*16 + d*8 + w
    if (tid < 128) {
        int gt = tid >> 5, rest = tid & 31;
        const float* P = (gt == 0) ? fP : (gt == 1) ? iP : (gt == 2) ? gP : oP;
        int g = (rest >> 4) & 1, d = (rest >> 3) & 1, w = rest & 7;
        const float* p3 = P + (((g * 2 + d) * 8 + w) * 3);
        float a = 0.5f * p3[0], b = 0.5f * p3[1], c = 0.5f * p3[2];
        float ca = cosf(a), sa = sinf(a);
        float cb = cosf(b), sb = sinf(b);
        float cc = cosf(c), sc = sinf(c);
        c32 eb  = {cb, -sb};   // e^{-ib}
        c32 ebc = {cb,  sb};   // e^{+ib}
        c32 scx = {0.f, -sc};  // -i sin(c)
        // M = rz @ ry
        c32 m00 = { eb.x * ca,  eb.y * ca};
        c32 m01 = {-eb.x * sa, -eb.y * sa};
        c32 m10 = { ebc.x * sa, ebc.y * sa};
        c32 m11 = { ebc.x * ca, ebc.y * ca};
        // U = rx @ M, rx = [[cc, -i sc],[-i sc, cc]]
        c32 U00 = cadd(c32{cc * m00.x, cc * m00.y}, cmul(scx, m10));
        c32 U01 = cadd(c32{cc * m01.x, cc * m01.y}, cmul(scx, m11));
        c32 U10 = cadd(cmul(scx, m00), c32{cc * m10.x, cc * m10.y});
        c32 U11 = cadd(cmul(scx, m01), c32{cc * m11.x, cc * m11.y});
        float* dst = ws + WS_U + tid * 8;
        dst[0] = U00.x; dst[1] = U00.y; dst[2] = U01.x; dst[3] = U01.y;
        dst[4] = U10.x; dst[5] = U10.y; dst[6] = U11.x; dst[7] = U11.y;
    }
}

// One block per (t,b) row: Xq[row][q] = dot(inputs[row], Wxq[q]) + bq[q]
__global__ void xq_kernel(const float* __restrict__ inputs, float* __restrict__ ws)
{
    __shared__ float xs[512];
    int row = blockIdx.x;           // t*64 + b
    int tid = threadIdx.x;          // 256
    xs[tid]       = inputs[row * 512 + tid];
    xs[tid + 256] = inputs[row * 512 + 256 + tid];
    __syncthreads();
    int g = tid >> 5, j = tid & 31;
    const float* w = ws + WS_WXQ + g * 512;
    float acc = 0.f;
    #pragma unroll 4
    for (int i = 0; i < 16; ++i) acc += xs[j + 32 * i] * w[j + 32 * i];
    acc += __shfl_xor(acc, 1);  acc += __shfl_xor(acc, 2);
    acc += __shfl_xor(acc, 4);  acc += __shfl_xor(acc, 8);
    acc += __shfl_xor(acc, 16);
    if (j == 0) ws[WS_XQ + row * 8 + g] = acc + ws[WS_BQ + g];
}

__global__ __launch_bounds__(256)
void recurrence_kernel(const float* __restrict__ W_q2h,
                       const float* __restrict__ ws,
                       float* __restrict__ out)
{
    __shared__ float sWhq[8 * 512];   // [q][h]
    __shared__ float sW2h[8 * 512];   // [q][h]  (transposed from global [h][q])
    __shared__ float sU[128 * 8];
    __shared__ float shx[512];
    __shared__ float sqin[8];
    __shared__ float sexp[4][8];

    int tid = threadIdx.x;   // 256
    int b   = blockIdx.x;    // 64

    for (int i = tid; i < 4096; i += 256) sWhq[i] = ws[WS_WHQ + i];
    for (int i = tid; i < 4096; i += 256) {
        int h = i >> 3, q = i & 7;
        sW2h[q * 512 + h] = W_q2h[i];
    }
    for (int i = tid; i < 1024; i += 256) sU[i] = ws[WS_U + i];
    shx[tid] = 0.f; shx[tid + 256] = 0.f;
    float c0 = 0.f, c1 = 0.f;
    __syncthreads();

    int wv   = tid >> 6;     // gate type: 0=f 1=i 2=g 3=o
    int lane = tid & 63;
    int grp  = tid >> 5, j = tid & 31;

    for (int t = 0; t < T_STEPS; ++t) {
        // ---- phase 1: qin[g] = Xq[t,b,g] + dot(hx, Whq[g]) ----
        {
            const float* w = sWhq + grp * 512;
            float acc = 0.f;
            #pragma unroll 4
            for (int i = 0; i < 16; ++i) acc += shx[j + 32 * i] * w[j + 32 * i];
            acc += __shfl_xor(acc, 1);  acc += __shfl_xor(acc, 2);
            acc += __shfl_xor(acc, 4);  acc += __shfl_xor(acc, 8);
            acc += __shfl_xor(acc, 16);
            if (j == 0) sqin[grp] = acc + ws[WS_XQ + (t * 64 + b) * 8 + grp];
        }
        __syncthreads();

        // ---- phase 2: quantum circuit, one wave per gate type ----
        {
            float xq[8];
            #pragma unroll
            for (int q = 0; q < 8; ++q) xq[q] = sqin[q];

            for (int gl = 0; gl < 2; ++gl) {
                float ch[8], sh[8];
                #pragma unroll
                for (int q = 0; q < 8; ++q) {
                    float hh = 0.5f * xq[q];
                    sincosf(hh, &sh[q], &ch[q]);
                }
                // product state: lane holds k = 4*lane + r, qubit q <-> bit (7-q)
                c32 s[4];
                #pragma unroll
                for (int r = 0; r < 4; ++r) {
                    int k = 4 * lane + r;
                    float m = 1.f;
                    #pragma unroll
                    for (int q = 0; q < 8; ++q) m *= ((k >> (7 - q)) & 1) ? sh[q] : ch[q];
                    int pc = __popc(k) & 3;  // phase (-i)^pc
                    s[r] = (pc == 0) ? c32{m, 0.f} : (pc == 1) ? c32{0.f, -m}
                         : (pc == 2) ? c32{-m, 0.f} : c32{0.f, m};
                }
                #pragma unroll
                for (int d = 0; d < 2; ++d) {
                    const float* ub = sU + (((wv * 2 + gl) * 2 + d) * 8) * 8;
                    #pragma unroll
                    for (int w = 0; w < 8; ++w) {
                        c32 u00 = {ub[w * 8 + 0], ub[w * 8 + 1]};
                        c32 u01 = {ub[w * 8 + 2], ub[w * 8 + 3]};
                        c32 u10 = {ub[w * 8 + 4], ub[w * 8 + 5]};
                        c32 u11 = {ub[w * 8 + 6], ub[w * 8 + 7]};
                        const int jb = 7 - w;
                        if (jb >= 2) {
                            const int lmask = 1 << (jb - 2);
                            int mybit = (lane >> (jb - 2)) & 1;
                            c32 ua, ubb;
                            ua.x  = mybit ? u10.x : u00.x;  ua.y  = mybit ? u10.y : u00.y;
                            ubb.x = mybit ? u11.x : u01.x;  ubb.y = mybit ? u11.y : u01.y;
                            #pragma unroll
                            for (int r = 0; r < 4; ++r) {
                                c32 p;
                                p.x = __shfl_xor(s[r].x, lmask);
                                p.y = __shfl_xor(s[r].y, lmask);
                                c32 q0, q1;  // q0 = amp with bit=0, q1 = amp with bit=1
                                q0.x = mybit ? p.x : s[r].x;  q0.y = mybit ? p.y : s[r].y;
                                q1.x = mybit ? s[r].x : p.x;  q1.y = mybit ? s[r].y : p.y;
                                s[r] = cadd(cmul(ua, q0), cmul(ubb, q1));
                            }
                        } else if (jb == 1) {      // pairs (r0,r2),(r1,r3)
                            c32 a0 = s[0], b0 = s[2], a1 = s[1], b1 = s[3];
                            s[0] = cadd(cmul(u00, a0), cmul(u01, b0));
                            s[2] = cadd(cmul(u10, a0), cmul(u11, b0));
                            s[1] = cadd(cmul(u00, a1), cmul(u01, b1));
                            s[3] = cadd(cmul(u10, a1), cmul(u11, b1));
                        } else {                   // jb==0: pairs (r0,r1),(r2,r3)
                            c32 a0 = s[0], b0 = s[1], a1 = s[2], b1 = s[3];
                            s[0] = cadd(cmul(u00, a0), cmul(u01, b0));
                            s[1] = cadd(cmul(u10, a0), cmul(u11, b0));
                            s[2] = cadd(cmul(u00, a1), cmul(u01, b1));
                            s[3] = cadd(cmul(u10, a1), cmul(u11, b1));
                        }
                    }
                    // CNOT chain c=0..6 (control c -> bit 7-c, target c+1 -> bit 6-c)
                    #pragma unroll
                    for (int c = 0; c < 5; ++c) {
                        const int jt = 6 - c;
                        const int lmask = 1 << (jt - 2);
                        int ctrl = (lane >> (jt - 1)) & 1;
                        #pragma unroll
                        for (int r = 0; r < 4; ++r) {
                            float px = __shfl_xor(s[r].x, lmask);
                            float py = __shfl_xor(s[r].y, lmask);
                            if (ctrl) { s[r].x = px; s[r].y = py; }
                        }
                    }
                    if (lane & 1) { // c=5: ctrl bit2(lane bit0), tgt bit1: swap r0<->r2, r1<->r3
                        c32 t0 = s[0]; s[0] = s[2]; s[2] = t0;
                        c32 t1 = s[1]; s[1] = s[3]; s[3] = t1;
                    }
                    { // c=6: ctrl bit1 (r>=2), tgt bit0: swap r2<->r3
                        c32 t2 = s[2]; s[2] = s[3]; s[3] = t2;
                    }
                }
                // expectations <Z_q>
                float p0 = s[0].x * s[0].x + s[0].y * s[0].y;
                float p1 = s[1].x * s[1].x + s[1].y * s[1].y;
                float p2 = s[2].x * s[2].x + s[2].y * s[2].y;
                float p3 = s[3].x * s[3].x + s[3].y * s[3].y;
                float psum = p0 + p1 + p2 + p3;
                float e[8];
                #pragma unroll
                for (int q = 0; q < 6; ++q)
                    e[q] = ((lane >> (5 - q)) & 1) ? -psum : psum;
                e[6] = (p0 + p1) - (p2 + p3);
                e[7] = (p0 + p2) - (p1 + p3);
                #pragma unroll
                for (int m = 1; m <= 32; m <<= 1) {
                    #pragma unroll
                    for (int q = 0; q < 8; ++q) e[q] += __shfl_xor(e[q], m);
                }
                #pragma unroll
                for (int q = 0; q < 8; ++q) xq[q] = e[q];
            }
            if (lane == 0) {
                #pragma unroll
                for (int q = 0; q < 8; ++q) sexp[wv][q] = xq[q];
            }
        }
        __syncthreads();

        // ---- phase 3: gates + LSTM update ----
        {
            float* so = out + (size_t)(t * 64 + b) * 512;
            #pragma unroll
            for (int hh = 0; hh < 2; ++hh) {
                int h = tid + hh * 256;
                float pf = 0.f, pi = 0.f, pg = 0.f, po = 0.f;
                #pragma unroll
                for (int q = 0; q < 8; ++q) {
                    float wq = sW2h[q * 512 + h];
                    pf += sexp[0][q] * wq;
                    pi += sexp[1][q] * wq;
                    pg += sexp[2][q] * wq;
                    po += sexp[3][q] * wq;
                }
                float f  = 1.f / (1.f + expf(-pf));
                float ii = 1.f / (1.f + expf(-pi));
                float g  = tanhf(pg);
                float o  = 1.f / (1.f + expf(-po));
                float cr = (hh ? c1 : c0);
                cr = f * cr + ii * g;
                float hn = o * tanhf(cr);
                if (hh) c1 = cr; else c0 = cr;
                shx[h] = hn;
                so[h]  = hn;
            }
        }
        __syncthreads();
    }

    // final hx, cx
    float* hx_out = out + (size_t)T_STEPS * 64 * 512;
    float* cx_out = hx_out + 64 * 512;
    hx_out[b * 512 + tid]       = shx[tid];
    hx_out[b * 512 + tid + 256] = shx[tid + 256];
    cx_out[b * 512 + tid]       = c0;
    cx_out[b * 512 + tid + 256] = c1;
}

extern "C" void kernel_launch(void* const* d_in, const int* in_sizes, int n_in,
                              void* d_out, int out_size, void* d_ws, size_t ws_size,
                              hipStream_t stream)
{
    const float* inputs = (const float*)d_in[0];
    const float* W_proj = (const float*)d_in[1];
    const float* b_proj = (const float*)d_in[2];
    const float* W_toq  = (const float*)d_in[3];
    const float* W_q2h  = (const float*)d_in[4];
    const float* fP     = (const float*)d_in[5];
    const float* iP     = (const float*)d_in[6];
    const float* gP     = (const float*)d_in[7];
    const float* oP     = (const float*)d_in[8];
    float* ws  = (float*)d_ws;
    float* out = (float*)d_out;

    precompute_kernel<<<1, 256, 0, stream>>>(W_proj, b_proj, W_toq, fP, iP, gP, oP, ws);
    xq_kernel<<<T_STEPS * BATCH, 256, 0, stream>>>(inputs, ws);
    recurrence_kernel<<<BATCH, 256, 0, stream>>>(W_q2h, ws, out);
}

// Round 2
// 261.082 us; speedup vs baseline: 1.8854x; 1.8854x over previous
//
#include <hip/hip_runtime.h>
#include <math.h>

#define T_STEPS 32
#define BATCH 64

// ws layout (floats)
#define WS_WXQ 0        // [8][512]
#define WS_WHQ 4096     // [8][512]
#define WS_BQ  8192     // [8]
#define WS_U   8208     // 128 matrices * 8 floats
#define WS_XQ  9232     // [32*64][8]

struct c32 { float x, y; };
__device__ inline c32 cmul(c32 a, c32 b){ return {a.x*b.x - a.y*b.y, a.x*b.y + a.y*b.x}; }
__device__ inline c32 cadd(c32 a, c32 b){ return {a.x+b.x, a.y+b.y}; }

__device__ inline float fast_sigmoid(float x){ return 1.f/(1.f + __expf(-x)); }
__device__ inline float fast_tanh(float x){ float e = __expf(2.f*x); return 1.f - 2.f/(e+1.f); }

__global__ void precompute_kernel(const float* __restrict__ W_proj,
                                  const float* __restrict__ b_proj,
                                  const float* __restrict__ W_toq,
                                  const float* __restrict__ fP, const float* __restrict__ iP,
                                  const float* __restrict__ gP, const float* __restrict__ oP,
                                  float* __restrict__ ws)
{
    int tid = threadIdx.x;
    int blk = blockIdx.x;
    if (blk < 32) {
        int idx = blk * 256 + tid;         // 0..8191
        int q = idx >> 10, dd = idx & 1023;
        float acc = 0.f;
        for (int p = 0; p < 64; ++p) acc += W_toq[q * 64 + p] * W_proj[p * 1024 + dd];
        if (dd < 512) ws[WS_WXQ + q * 512 + dd] = acc;
        else          ws[WS_WHQ + q * 512 + (dd - 512)] = acc;
        if (idx < 8) {
            float a2 = 0.f;
            for (int p = 0; p < 64; ++p) a2 += W_toq[idx * 64 + p] * b_proj[p];
            ws[WS_BQ + idx] = a2;
        }
    } else if (tid < 128) {
        int gt = tid >> 5, rest = tid & 31;
        const float* P = (gt == 0) ? fP : (gt == 1) ? iP : (gt == 2) ? gP : oP;
        int g = (rest >> 4) & 1, d = (rest >> 3) & 1, w = rest & 7;
        const float* p3 = P + (((g * 2 + d) * 8 + w) * 3);
        float a = 0.5f * p3[0], b = 0.5f * p3[1], c = 0.5f * p3[2];
        float ca = cosf(a), sa = sinf(a);
        float cb = cosf(b), sb = sinf(b);
        float cc = cosf(c), sc = sinf(c);
        c32 eb  = {cb, -sb};
        c32 ebc = {cb,  sb};
        c32 scx = {0.f, -sc};
        c32 m00 = { eb.x * ca,  eb.y * ca};
        c32 m01 = {-eb.x * sa, -eb.y * sa};
        c32 m10 = { ebc.x * sa, ebc.y * sa};
        c32 m11 = { ebc.x * ca, ebc.y * ca};
        c32 U00 = cadd(c32{cc * m00.x, cc * m00.y}, cmul(scx, m10));
        c32 U01 = cadd(c32{cc * m01.x, cc * m01.y}, cmul(scx, m11));
        c32 U10 = cadd(cmul(scx, m00), c32{cc * m10.x, cc * m10.y});
        c32 U11 = cadd(cmul(scx, m01), c32{cc * m11.x, cc * m11.y});
        float* dst = ws + WS_U + tid * 8;
        dst[0] = U00.x; dst[1] = U00.y; dst[2] = U01.x; dst[3] = U01.y;
        dst[4] = U10.x; dst[5] = U10.y; dst[6] = U11.x; dst[7] = U11.y;
    }
}

__global__ void xq_kernel(const float* __restrict__ inputs, float* __restrict__ ws)
{
    __shared__ float xs[512];
    int row = blockIdx.x;           // t*64 + b
    int tid = threadIdx.x;          // 256
    xs[tid]       = inputs[row * 512 + tid];
    xs[tid + 256] = inputs[row * 512 + 256 + tid];
    __syncthreads();
    int g = tid >> 5, j = tid & 31;
    const float* w = ws + WS_WXQ + g * 512;
    float acc = 0.f;
    #pragma unroll 4
    for (int i = 0; i < 16; ++i) acc += xs[j + 32 * i] * w[j + 32 * i];
    acc += __shfl_xor(acc, 1);  acc += __shfl_xor(acc, 2);
    acc += __shfl_xor(acc, 4);  acc += __shfl_xor(acc, 8);
    acc += __shfl_xor(acc, 16);
    if (j == 0) ws[WS_XQ + row * 8 + g] = acc + ws[WS_BQ + g];
}

__global__ __launch_bounds__(256)
void recurrence_kernel(const float* __restrict__ W_q2h,
                       const float* __restrict__ ws,
                       float* __restrict__ out)
{
    __shared__ float sU[1024];
    __shared__ float sXq[T_STEPS * 8];
    __shared__ float sexp[4][8];
    __shared__ float qpart[4][8];

    int tid = threadIdx.x;   // 256
    int b   = blockIdx.x;    // 64
    int wv  = tid >> 6;      // gate: 0=f 1=i 2=g 3=o
    int lane = tid & 63;

    for (int i = tid; i < 1024; i += 256) sU[i] = ws[WS_U + i];
    sXq[tid] = ws[WS_XQ + ((tid >> 3) * 64 + b) * 8 + (tid & 7)];
    if (tid < 32) ((float*)qpart)[tid] = 0.f;

    // register-resident weights
    float w2h_a[8], w2h_b[8], wh_a[8], wh_b[8];
    #pragma unroll
    for (int q = 0; q < 8; ++q) {
        w2h_a[q] = W_q2h[tid * 8 + q];
        w2h_b[q] = W_q2h[(tid + 256) * 8 + q];
        wh_a[q]  = ws[WS_WHQ + q * 512 + tid];
        wh_b[q]  = ws[WS_WHQ + q * 512 + tid + 256];
    }
    float c0 = 0.f, c1 = 0.f, h0 = 0.f, h1 = 0.f;

    // lane-derived Gray-map bits: qubit q (q=0..5) uses m-bit (7-q)
    int l = lane;
    int mb0 = (l >> 5) & 1;
    int mb1 = ((l >> 4) ^ (l >> 5)) & 1;
    int mb2 = ((l >> 3) ^ (l >> 4)) & 1;
    int mb3 = ((l >> 2) ^ (l >> 3)) & 1;
    int mb4 = ((l >> 1) ^ (l >> 2)) & 1;
    int mb5 = (l ^ (l >> 1)) & 1;
    int l0 = l & 1;

    __syncthreads();

    for (int t = 0; t < T_STEPS; ++t) {
        // ---- (a) qin: Xq + sum of per-wave h-partials ----
        float ang[8];
        #pragma unroll
        for (int q = 0; q < 8; ++q)
            ang[q] = 0.5f * (sXq[t * 8 + q] + qpart[0][q] + qpart[1][q] + qpart[2][q] + qpart[3][q]);

        // ---- (b) quantum circuit for gate-type wv ----
        float e[8];
        #pragma unroll
        for (int gl = 0; gl < 2; ++gl) {
            // d=0 rotations folded into product 2-vectors u_q = U0_q (cos, -i sin)
            c32 u0[8], u1[8];
            const float4* v4 = (const float4*)(sU + (wv * 4 + gl * 2) * 64);
            #pragma unroll
            for (int q = 0; q < 8; ++q) {
                float sh = __sinf(ang[q]), ch = __cosf(ang[q]);
                float4 a4 = v4[q * 2], b4 = v4[q * 2 + 1];
                u0[q].x = ch * a4.x + sh * a4.w;   // ch*U00 + sh*(-i U01)
                u0[q].y = ch * a4.y - sh * a4.z;
                u1[q].x = ch * b4.x + sh * b4.w;
                u1[q].y = ch * b4.y - sh * b4.z;
            }
            // d=0 CNOT chain = Gray permutation: amp[j] = prod_q u_q[bit_{7-q}(j ^ (j>>1))]
            c32 P = mb0 ? u1[0] : u0[0];
            P = cmul(P, mb1 ? u1[1] : u0[1]);
            P = cmul(P, mb2 ? u1[2] : u0[2]);
            P = cmul(P, mb3 ? u1[3] : u0[3]);
            P = cmul(P, mb4 ? u1[4] : u0[4]);
            P = cmul(P, mb5 ? u1[5] : u0[5]);
            c32 Q0 = cmul(P, l0 ? u1[6] : u0[6]);  // r1=0: m1 = l0
            c32 Q1 = cmul(P, l0 ? u0[6] : u1[6]);  // r1=1: m1 = l0^1
            c32 s[4];
            s[0] = cmul(Q0, u0[7]);  // r=0: m0=0
            s[1] = cmul(Q0, u1[7]);  // r=1: m0=1
            s[2] = cmul(Q1, u1[7]);  // r=2: m0=1
            s[3] = cmul(Q1, u0[7]);  // r=3: m0=0

            // d=1 rotations: full statevector wire updates
            const float4* u4 = (const float4*)(sU + (wv * 4 + gl * 2 + 1) * 64);
            #pragma unroll
            for (int w = 0; w < 8; ++w) {
                float4 a4 = u4[w * 2], b4 = u4[w * 2 + 1];
                c32 u00 = {a4.x, a4.y}, u01 = {a4.z, a4.w};
                c32 u10 = {b4.x, b4.y}, u11 = {b4.z, b4.w};
                const int jb = 7 - w;
                if (jb >= 2) {
                    const int lmask = 1 << (jb - 2);
                    int mybit = (lane >> (jb - 2)) & 1;
                    c32 ua, ubb;
                    ua.x  = mybit ? u10.x : u00.x;  ua.y  = mybit ? u10.y : u00.y;
                    ubb.x = mybit ? u11.x : u01.x;  ubb.y = mybit ? u11.y : u01.y;
                    #pragma unroll
                    for (int r = 0; r < 4; ++r) {
                        c32 p;
                        p.x = __shfl_xor(s[r].x, lmask);
                        p.y = __shfl_xor(s[r].y, lmask);
                        c32 q0, q1;
                        q0.x = mybit ? p.x : s[r].x;  q0.y = mybit ? p.y : s[r].y;
                        q1.x = mybit ? s[r].x : p.x;  q1.y = mybit ? s[r].y : p.y;
                        s[r] = cadd(cmul(ua, q0), cmul(ubb, q1));
                    }
                } else if (jb == 1) {      // pairs (r0,r2),(r1,r3)
                    c32 a0 = s[0], b0 = s[2], a1 = s[1], b1 = s[3];
                    s[0] = cadd(cmul(u00, a0), cmul(u01, b0));
                    s[2] = cadd(cmul(u10, a0), cmul(u11, b0));
                    s[1] = cadd(cmul(u00, a1), cmul(u01, b1));
                    s[3] = cadd(cmul(u10, a1), cmul(u11, b1));
                } else {                   // jb==0: pairs (r0,r1),(r2,r3)
                    c32 a0 = s[0], b0 = s[1], a1 = s[2], b1 = s[3];
                    s[0] = cadd(cmul(u00, a0), cmul(u01, b0));
                    s[1] = cadd(cmul(u10, a0), cmul(u11, b0));
                    s[2] = cadd(cmul(u00, a1), cmul(u01, b1));
                    s[3] = cadd(cmul(u10, a1), cmul(u11, b1));
                }
            }

            // d=1 CNOT chain folded into signs: e_q = sum_j parity(j >> (7-q)) |amp_j|^2
            float p0 = s[0].x * s[0].x + s[0].y * s[0].y;
            float p1 = s[1].x * s[1].x + s[1].y * s[1].y;
            float p2 = s[2].x * s[2].x + s[2].y * s[2].y;
            float p3 = s[3].x * s[3].x + s[3].y * s[3].y;
            float w0 = (p0 + p1) + (p2 + p3);
            float w6 = (p0 + p1) - (p2 + p3);
            float w7 = (p0 - p1) - (p2 - p3);
            // Walsh-Hadamard butterfly over lanes
            #pragma unroll
            for (int st = 0; st < 6; ++st) {
                int m = 1 << st, bit = (l >> st) & 1;
                float v0 = __shfl_xor(w0, m); w0 = bit ? v0 - w0 : v0 + w0;
                float v6 = __shfl_xor(w6, m); w6 = bit ? v6 - w6 : v6 + w6;
                float v7 = __shfl_xor(w7, m); w7 = bit ? v7 - w7 : v7 + w7;
            }
            e[0] = __shfl(w0, 32); e[1] = __shfl(w0, 48); e[2] = __shfl(w0, 56);
            e[3] = __shfl(w0, 60); e[4] = __shfl(w0, 62); e[5] = __shfl(w0, 63);
            e[6] = __shfl(w6, 63); e[7] = __shfl(w7, 63);
            if (gl == 0) {
                #pragma unroll
                for (int q = 0; q < 8; ++q) ang[q] = 0.5f * e[q];
            }
        }
        if (lane == 0) {
            #pragma unroll
            for (int q = 0; q < 8; ++q) sexp[wv][q] = e[q];
        }
        __syncthreads();

        // ---- (d) LSTM cell, 2 h per thread, weights in registers ----
        {
            float pf0 = 0, pi0 = 0, pg0 = 0, po0 = 0, pf1 = 0, pi1 = 0, pg1 = 0, po1 = 0;
            #pragma unroll
            for (int q = 0; q < 8; ++q) {
                float e0 = sexp[0][q], e1 = sexp[1][q], e2 = sexp[2][q], e3 = sexp[3][q];
                pf0 += e0 * w2h_a[q]; pi0 += e1 * w2h_a[q]; pg0 += e2 * w2h_a[q]; po0 += e3 * w2h_a[q];
                pf1 += e0 * w2h_b[q]; pi1 += e1 * w2h_b[q]; pg1 += e2 * w2h_b[q]; po1 += e3 * w2h_b[q];
            }
            float f = fast_sigmoid(pf0), ii = fast_sigmoid(pi0);
            float g = fast_tanh(pg0),   o  = fast_sigmoid(po0);
            c0 = f * c0 + ii * g;  h0 = o * fast_tanh(c0);
            f = fast_sigmoid(pf1); ii = fast_sigmoid(pi1);
            g = fast_tanh(pg1);    o  = fast_sigmoid(po1);
            c1 = f * c1 + ii * g;  h1 = o * fast_tanh(c1);
            float* so = out + (size_t)(t * 64 + b) * 512;
            so[tid] = h0; so[tid + 256] = h1;
        }

        // ---- (e) qin partials for next step: octet reduce + cross-octet ----
        {
            float part[8];
            #pragma unroll
            for (int q = 0; q < 8; ++q) part[q] = h0 * wh_a[q] + h1 * wh_b[q];
            #pragma unroll
            for (int st = 0; st < 3; ++st) {
                int m = 1 << st;
                #pragma unroll
                for (int q = 0; q < 8; ++q) part[q] += __shfl_xor(part[q], m);
            }
            int sel = lane & 7;
            float y = sel == 0 ? part[0] : sel == 1 ? part[1] : sel == 2 ? part[2] : sel == 3 ? part[3]
                    : sel == 4 ? part[4] : sel == 5 ? part[5] : sel == 6 ? part[6] : part[7];
            y += __shfl_xor(y, 8); y += __shfl_xor(y, 16); y += __shfl_xor(y, 32);
            if (lane < 8) qpart[wv][lane] = y;
        }
        __syncthreads();
    }

    // final hx, cx from registers
    float* hx_out = out + (size_t)T_STEPS * 64 * 512;
    float* cx_out = hx_out + 64 * 512;
    hx_out[b * 512 + tid]       = h0;
    hx_out[b * 512 + tid + 256] = h1;
    cx_out[b * 512 + tid]       = c0;
    cx_out[b * 512 + tid + 256] = c1;
}

extern "C" void kernel_launch(void* const* d_in, const int* in_sizes, int n_in,
                              void* d_out, int out_size, void* d_ws, size_t ws_size,
                              hipStream_t stream)
{
    const float* inputs = (const float*)d_in[0];
    const float* W_proj = (const float*)d_in[1];
    const float* b_proj = (const float*)d_in[2];
    const float* W_toq  = (const float*)d_in[3];
    const float* W_q2h  = (const float*)d_in[4];
    const float* fP     = (const float*)d_in[5];
    const float* iP     = (const float*)d_in[6];
    const float* gP     = (const float*)d_in[7];
    const float* oP     = (const float*)d_in[8];
    float* ws  = (float*)d_ws;
    float* out = (float*)d_out;

    precompute_kernel<<<33, 256, 0, stream>>>(W_proj, b_proj, W_toq, fP, iP, gP, oP, ws);
    xq_kernel<<<T_STEPS * BATCH, 256, 0, stream>>>(inputs, ws);
    recurrence_kernel<<<BATCH, 256, 0, stream>>>(W_q2h, ws, out);
}